// Round 3
// baseline (5983.133 us; speedup 1.0000x reference)
//
#include <hip/hip_runtime.h>
#include <hip/hip_bf16.h>

#define ND 128
#define ED 128
#define NIN 128
#define EIN 291
#define HH 64

// Zero a float buffer.
__global__ __launch_bounds__(256) void zero_k(float* __restrict__ p, int n4)
{
    int idx = blockIdx.x * 256 + threadIdx.x;
    if (idx < n4) ((float4*)p)[idx] = make_float4(0.f, 0.f, 0.f, 0.f);
}

// nf0/nf = MLP(x): NIN->128 (ReLU) ->ND. One block (128 thr) per node.
__global__ __launch_bounds__(128) void node_embed_k(
    const float* __restrict__ x, const float* __restrict__ w0, const float* __restrict__ b0,
    const float* __restrict__ w1, const float* __restrict__ b1,
    float* __restrict__ nf0, float* __restrict__ nf)
{
    int node = blockIdx.x;
    int t = threadIdx.x;
    __shared__ float xin[NIN];
    __shared__ float h[128];
    xin[t] = x[node * NIN + t];
    __syncthreads();
    float acc = b0[t];
#pragma unroll 8
    for (int k = 0; k < NIN; k++) acc += xin[k] * w0[k * 128 + t];
    h[t] = fmaxf(acc, 0.f);
    __syncthreads();
    float acc2 = b1[t];
#pragma unroll 8
    for (int k = 0; k < 128; k++) acc2 += h[k] * w1[k * ND + t];
    nf0[node * ND + t] = acc2;
    nf[node * ND + t] = acc2;
}

// ef0/ef = MLP(edge_attr): EIN->64 (ReLU) ->ED. One block (128 thr) per edge.
__global__ __launch_bounds__(128) void edge_embed_k(
    const float* __restrict__ ea, const float* __restrict__ w0, const float* __restrict__ b0,
    const float* __restrict__ w1, const float* __restrict__ b1,
    float* __restrict__ ef0, float* __restrict__ ef)
{
    int e = blockIdx.x;
    int t = threadIdx.x;
    __shared__ float ein[EIN];
    __shared__ float h[HH];
    for (int kk = t; kk < EIN; kk += 128) ein[kk] = ea[(size_t)e * EIN + kk];
    __syncthreads();
    if (t < HH) {
        float acc = b0[t];
#pragma unroll 8
        for (int k = 0; k < EIN; k++) acc += ein[k] * w0[k * HH + t];
        h[t] = fmaxf(acc, 0.f);
    }
    __syncthreads();
    float acc = b1[t];
#pragma unroll
    for (int k = 0; k < HH; k++) acc += h[k] * w1[k * ED + t];
    ef0[(size_t)e * ED + t] = acc;
    ef[(size_t)e * ED + t] = acc;
}

// One MPN step, fused per edge: edge MLP (768->64->128, ReLU both, ef updated
// in place) + message MLP (384->128, ReLU) + atomic scatter-add into nfn[i].
__global__ __launch_bounds__(128) void edge_step_k(
    const int* __restrict__ srcj, const int* __restrict__ tgti,
    const float* __restrict__ nf0, const float* __restrict__ nfc,
    const float* __restrict__ ef0, float* __restrict__ ef,
    float* __restrict__ nfn,
    const float* __restrict__ mew0, const float* __restrict__ meb0,
    const float* __restrict__ mew1, const float* __restrict__ meb1,
    const float* __restrict__ mnw0, const float* __restrict__ mnb0)
{
    int e = blockIdx.x;
    int t = threadIdx.x;
    int i = tgti[e], j = srcj[e];
    __shared__ float in[768];
    __shared__ float h[HH];
    __shared__ float efn[ED];
    in[t]        = nf0[(size_t)i * ND + t];
    in[128 + t]  = nfc[(size_t)i * ND + t];
    in[256 + t]  = nf0[(size_t)j * ND + t];
    in[384 + t]  = nfc[(size_t)j * ND + t];
    in[512 + t]  = ef0[(size_t)e * ED + t];
    in[640 + t]  = ef[(size_t)e * ED + t];
    __syncthreads();
    if (t < HH) {
        float acc = meb0[t];
#pragma unroll 8
        for (int k = 0; k < 768; k++) acc += in[k] * mew0[k * HH + t];
        h[t] = fmaxf(acc, 0.f);
    }
    __syncthreads();
    {
        float acc = meb1[t];
#pragma unroll
        for (int k = 0; k < HH; k++) acc += h[k] * mew1[k * ED + t];
        float v = fmaxf(acc, 0.f);
        efn[t] = v;
        ef[(size_t)e * ED + t] = v;
    }
    __syncthreads();
    {
        float acc = mnb0[t];
#pragma unroll 8
        for (int k = 0; k < 256; k++) acc += in[k] * mnw0[k * ND + t];
#pragma unroll 8
        for (int k = 0; k < 128; k++) acc += efn[k] * mnw0[(256 + k) * ND + t];
        atomicAdd(&nfn[(size_t)i * ND + t], fmaxf(acc, 0.f));
    }
}

// out = MLP(ef): ED->64 (ReLU) ->32 (ReLU) ->1. One block (64 thr) per edge.
__global__ __launch_bounds__(64) void classify_k(
    const float* __restrict__ ef,
    const float* __restrict__ cw0, const float* __restrict__ cb0,
    const float* __restrict__ cw1, const float* __restrict__ cb1,
    const float* __restrict__ cw2, const float* __restrict__ cb2,
    float* __restrict__ out)
{
    int e = blockIdx.x;
    int t = threadIdx.x;
    __shared__ float efs[ED];
    __shared__ float h0[64];
    __shared__ float h1[32];
    efs[t] = ef[(size_t)e * ED + t];
    efs[64 + t] = ef[(size_t)e * ED + 64 + t];
    __syncthreads();
    float acc = cb0[t];
#pragma unroll 8
    for (int k = 0; k < ED; k++) acc += efs[k] * cw0[k * 64 + t];
    h0[t] = fmaxf(acc, 0.f);
    __syncthreads();
    if (t < 32) {
        float a = cb1[t];
#pragma unroll
        for (int k = 0; k < 64; k++) a += h0[k] * cw1[k * 32 + t];
        h1[t] = fmaxf(a, 0.f);
    }
    __syncthreads();
    if (t == 0) {
        float a = cb2[0];
#pragma unroll
        for (int k = 0; k < 32; k++) a += h1[k] * cw2[k];
        out[e] = a;
    }
}

extern "C" void kernel_launch(void* const* d_in, const int* in_sizes, int n_in,
                              void* d_out, int out_size, void* d_ws, size_t ws_size,
                              hipStream_t stream)
{
    const float* x    = (const float*)d_in[0];
    const float* ea   = (const float*)d_in[1];
    const int*   eidx = (const int*)d_in[2];
    const float* new0 = (const float*)d_in[3];  const float* neb0 = (const float*)d_in[4];
    const float* new1 = (const float*)d_in[5];  const float* neb1 = (const float*)d_in[6];
    const float* eew0 = (const float*)d_in[7];  const float* eeb0 = (const float*)d_in[8];
    const float* eew1 = (const float*)d_in[9];  const float* eeb1 = (const float*)d_in[10];
    const float* mew0 = (const float*)d_in[11]; const float* meb0 = (const float*)d_in[12];
    const float* mew1 = (const float*)d_in[13]; const float* meb1 = (const float*)d_in[14];
    const float* mnw0 = (const float*)d_in[15]; const float* mnb0 = (const float*)d_in[16];
    const float* cw0  = (const float*)d_in[17]; const float* cb0  = (const float*)d_in[18];
    const float* cw1  = (const float*)d_in[19]; const float* cb1  = (const float*)d_in[20];
    const float* cw2  = (const float*)d_in[21]; const float* cb2  = (const float*)d_in[22];

    const int N = in_sizes[0] / NIN;   // 20000
    const int E = in_sizes[2] / 2;     // 100000
    const int* srcj = eidx;            // edge_index[0] = j (source)
    const int* tgti = eidx + E;        // edge_index[1] = i (target)

    float* ws  = (float*)d_ws;
    float* nf0 = ws;                                  // N*ND
    float* nfA = nf0 + (size_t)N * ND;                // N*ND
    float* nfB = nfA + (size_t)N * ND;                // N*ND
    float* ef0 = nfB + (size_t)N * ND;                // E*ED
    float* ef  = ef0 + (size_t)E * ED;                // E*ED

    node_embed_k<<<N, 128, 0, stream>>>(x, new0, neb0, new1, neb1, nf0, nfA);
    edge_embed_k<<<E, 128, 0, stream>>>(ea, eew0, eeb0, eew1, eeb1, ef0, ef);

    const int nf_elems = N * ND;            // 2,560,000 floats (divisible by 4)
    const int n4 = nf_elems / 4;
    const int zgrid = (n4 + 255) / 256;

    float* cur = nfA;
    float* nxt = nfB;
    for (int s = 0; s < 4; s++) {
        zero_k<<<zgrid, 256, 0, stream>>>(nxt, n4);
        edge_step_k<<<E, 128, 0, stream>>>(srcj, tgti, nf0, cur, ef0, ef, nxt,
                                           mew0, meb0, mew1, meb1, mnw0, mnb0);
        float* tmp = cur; cur = nxt; nxt = tmp;
    }

    classify_k<<<E, 64, 0, stream>>>(ef, cw0, cb0, cw1, cb1, cw2, cb2, (float*)d_out);
}

// Round 4
// 2837.597 us; speedup vs baseline: 2.1085x; 2.1085x over previous
//
#include <hip/hip_runtime.h>
#include <hip/hip_bf16.h>

#define ND 128
#define ED 128
#define NIN 128
#define EIN 291
#define HH 64
#define TE 16   // edges per block in tiled kernels

// Zero a float buffer.
__global__ __launch_bounds__(256) void zero_k(float* __restrict__ p, int n4)
{
    int idx = blockIdx.x * 256 + threadIdx.x;
    if (idx < n4) ((float4*)p)[idx] = make_float4(0.f, 0.f, 0.f, 0.f);
}

// nf0/nf = MLP(x): NIN->128 (ReLU) ->ND. One block (128 thr) per node. (small: 1.3 GF)
__global__ __launch_bounds__(128) void node_embed_k(
    const float* __restrict__ x, const float* __restrict__ w0, const float* __restrict__ b0,
    const float* __restrict__ w1, const float* __restrict__ b1,
    float* __restrict__ nf0, float* __restrict__ nf)
{
    int node = blockIdx.x;
    int t = threadIdx.x;
    __shared__ float xin[NIN];
    __shared__ float h[128];
    xin[t] = x[node * NIN + t];
    __syncthreads();
    float acc = b0[t];
#pragma unroll 8
    for (int k = 0; k < NIN; k++) acc += xin[k] * w0[k * 128 + t];
    h[t] = fmaxf(acc, 0.f);
    __syncthreads();
    float acc2 = b1[t];
#pragma unroll 8
    for (int k = 0; k < 128; k++) acc2 += h[k] * w1[k * ND + t];
    nf0[node * ND + t] = acc2;
    nf[node * ND + t] = acc2;
}

// ef0/ef = MLP(edge_attr): EIN->64 (ReLU) ->ED. TE edges per 256-thr block.
__global__ __launch_bounds__(256) void edge_embed_k(
    const float* __restrict__ ea, const float* __restrict__ w0, const float* __restrict__ b0,
    const float* __restrict__ w1, const float* __restrict__ b1,
    float* __restrict__ ef0, float* __restrict__ ef, int E)
{
    int t = threadIdx.x;
    int e0 = blockIdx.x * TE;
    __shared__ float in2[TE][EIN];
    __shared__ float h[TE][HH];
    // stage edge_attr rows (coalesced per row)
    for (int r = 0; r < TE; r++) {
        int e = e0 + r; if (e >= E) e = E - 1;
        for (int p = t; p < EIN; p += 256) in2[r][p] = ea[(size_t)e * EIN + p];
    }
    __syncthreads();
    // layer 1: 16 edges x 64 cols; thread: col c, 4 edges
    {
        int c = t & 63, eg = t >> 6;
        float acc[4];
#pragma unroll
        for (int q = 0; q < 4; q++) acc[q] = b0[c];
#pragma unroll 8
        for (int k = 0; k < EIN; k++) {
            float w = w0[k * HH + c];
#pragma unroll
            for (int q = 0; q < 4; q++) acc[q] += in2[eg * 4 + q][k] * w;
        }
#pragma unroll
        for (int q = 0; q < 4; q++) h[eg * 4 + q][c] = fmaxf(acc[q], 0.f);
    }
    __syncthreads();
    // layer 2: 16 edges x 128 cols; thread: col c2, 8 edges
    {
        int c2 = t & 127, eh = t >> 7;
        float acc[8];
#pragma unroll
        for (int q = 0; q < 8; q++) acc[q] = b1[c2];
#pragma unroll 8
        for (int k = 0; k < HH; k++) {
            float w = w1[k * ED + c2];
#pragma unroll
            for (int q = 0; q < 8; q++) acc[q] += h[eh * 8 + q][k] * w;
        }
#pragma unroll
        for (int q = 0; q < 8; q++) {
            int e = e0 + eh * 8 + q;
            if (e < E) {
                ef0[(size_t)e * ED + c2] = acc[q];
                ef[(size_t)e * ED + c2] = acc[q];
            }
        }
    }
}

// One MPN step, TE edges per 256-thr block: edge MLP (768->64->128, ReLU both,
// ef in place) + message MLP (384->128, ReLU) + atomic scatter-add into nfn[i].
__global__ __launch_bounds__(256) void edge_step_k(
    const int* __restrict__ srcj, const int* __restrict__ tgti,
    const float* __restrict__ nf0, const float* __restrict__ nfc,
    const float* __restrict__ ef0, float* __restrict__ ef,
    float* __restrict__ nfn,
    const float* __restrict__ mew0, const float* __restrict__ meb0,
    const float* __restrict__ mew1, const float* __restrict__ meb1,
    const float* __restrict__ mnw0, const float* __restrict__ mnb0, int E)
{
    int t = threadIdx.x;
    int e0 = blockIdx.x * TE;
    __shared__ float in[TE][768];
    __shared__ float h[TE][HH];
    __shared__ float efn[TE][ED];
    __shared__ int sidx[2 * TE];   // [0..TE): target i, [TE..2TE): source j
    if (t < 2 * TE) {
        int r = t & (TE - 1);
        int e = e0 + r; if (e >= E) e = E - 1;
        sidx[t] = (t < TE) ? tgti[e] : srcj[e];
    }
    __syncthreads();
    // stage [nf0_i | nf_i | nf0_j | nf_j | ef0_e | ef_e] per edge row
    for (int idx = t; idx < TE * 768; idx += 256) {
        int r = idx >> 9;          // wrong shift? 768 not pow2 — use div below
        (void)r;
        break;
    }
    {
        // per-row staging, coalesced 128-float segments
        for (int r = 0; r < TE; r++) {
            int e = e0 + r; if (e >= E) e = E - 1;
            int i = sidx[r], j = sidx[TE + r];
            int p = t;                       // 256 threads cover 2 segs of 128
            int seg = p >> 7, q = p & 127;   // seg 0..1
            in[r][seg * 128 + q]       = (seg == 0 ? nf0[(size_t)i * ND + q] : nfc[(size_t)i * ND + q]);
            in[r][256 + seg * 128 + q] = (seg == 0 ? nf0[(size_t)j * ND + q] : nfc[(size_t)j * ND + q]);
            in[r][512 + seg * 128 + q] = (seg == 0 ? ef0[(size_t)e * ED + q] : ef[(size_t)e * ED + q]);
        }
    }
    __syncthreads();
    // layer 1: 768 -> 64 (ReLU). thread: col c, 4 edges.
    {
        int c = t & 63, eg = t >> 6;
        float acc[4];
#pragma unroll
        for (int q = 0; q < 4; q++) acc[q] = meb0[c];
#pragma unroll 8
        for (int k = 0; k < 768; k++) {
            float w = mew0[k * HH + c];
#pragma unroll
            for (int q = 0; q < 4; q++) acc[q] += in[eg * 4 + q][k] * w;
        }
#pragma unroll
        for (int q = 0; q < 4; q++) h[eg * 4 + q][c] = fmaxf(acc[q], 0.f);
    }
    __syncthreads();
    // layer 2: 64 -> 128 (ReLU), ef updated in place. thread: col c2, 8 edges.
    {
        int c2 = t & 127, eh = t >> 7;
        float acc[8];
#pragma unroll
        for (int q = 0; q < 8; q++) acc[q] = meb1[c2];
#pragma unroll 8
        for (int k = 0; k < HH; k++) {
            float w = mew1[k * ED + c2];
#pragma unroll
            for (int q = 0; q < 8; q++) acc[q] += h[eh * 8 + q][k] * w;
        }
#pragma unroll
        for (int q = 0; q < 8; q++) {
            int r = eh * 8 + q;
            float v = fmaxf(acc[q], 0.f);
            efn[r][c2] = v;
            int e = e0 + r;
            if (e < E) ef[(size_t)e * ED + c2] = v;
        }
    }
    __syncthreads();
    // message: [x_i | efn] (384) -> 128 (ReLU), scatter-add at target i.
    {
        int c2 = t & 127, eh = t >> 7;
        float acc[8];
#pragma unroll
        for (int q = 0; q < 8; q++) acc[q] = mnb0[c2];
#pragma unroll 8
        for (int k = 0; k < 256; k++) {
            float w = mnw0[k * ND + c2];
#pragma unroll
            for (int q = 0; q < 8; q++) acc[q] += in[eh * 8 + q][k] * w;
        }
#pragma unroll 8
        for (int k = 0; k < 128; k++) {
            float w = mnw0[(256 + k) * ND + c2];
#pragma unroll
            for (int q = 0; q < 8; q++) acc[q] += efn[eh * 8 + q][k] * w;
        }
#pragma unroll
        for (int q = 0; q < 8; q++) {
            int r = eh * 8 + q;
            int e = e0 + r;
            if (e < E) atomicAdd(&nfn[(size_t)sidx[r] * ND + c2], fmaxf(acc[q], 0.f));
        }
    }
}

// out = MLP(ef): ED->64 (ReLU) ->32 (ReLU) ->1. TE edges per 256-thr block.
__global__ __launch_bounds__(256) void classify_k(
    const float* __restrict__ ef,
    const float* __restrict__ cw0, const float* __restrict__ cb0,
    const float* __restrict__ cw1, const float* __restrict__ cb1,
    const float* __restrict__ cw2, const float* __restrict__ cb2,
    float* __restrict__ out, int E)
{
    int t = threadIdx.x;
    int e0 = blockIdx.x * TE;
    __shared__ float efs[TE][ED];
    __shared__ float h0[TE][64];
    __shared__ float h1[TE][32];
    for (int r = 0; r < TE; r += 2) {
        int rr = r + (t >> 7);
        int e = e0 + rr; if (e >= E) e = E - 1;
        efs[rr][t & 127] = ef[(size_t)e * ED + (t & 127)];
    }
    __syncthreads();
    {
        int c = t & 63, eg = t >> 6;
        float acc[4];
#pragma unroll
        for (int q = 0; q < 4; q++) acc[q] = cb0[c];
#pragma unroll 8
        for (int k = 0; k < ED; k++) {
            float w = cw0[k * 64 + c];
#pragma unroll
            for (int q = 0; q < 4; q++) acc[q] += efs[eg * 4 + q][k] * w;
        }
#pragma unroll
        for (int q = 0; q < 4; q++) h0[eg * 4 + q][c] = fmaxf(acc[q], 0.f);
    }
    __syncthreads();
    {
        int c = t & 31, eg = t >> 5;   // 8 groups of 2 edges
        float acc[2];
#pragma unroll
        for (int q = 0; q < 2; q++) acc[q] = cb1[c];
#pragma unroll 8
        for (int k = 0; k < 64; k++) {
            float w = cw1[k * 32 + c];
#pragma unroll
            for (int q = 0; q < 2; q++) acc[q] += h0[eg * 2 + q][k] * w;
        }
#pragma unroll
        for (int q = 0; q < 2; q++) h1[eg * 2 + q][c] = fmaxf(acc[q], 0.f);
    }
    __syncthreads();
    if (t < TE) {
        int e = e0 + t;
        if (e < E) {
            float a = cb2[0];
#pragma unroll
            for (int k = 0; k < 32; k++) a += h1[t][k] * cw2[k];
            out[e] = a;
        }
    }
}

extern "C" void kernel_launch(void* const* d_in, const int* in_sizes, int n_in,
                              void* d_out, int out_size, void* d_ws, size_t ws_size,
                              hipStream_t stream)
{
    const float* x    = (const float*)d_in[0];
    const float* ea   = (const float*)d_in[1];
    const int*   eidx = (const int*)d_in[2];
    const float* new0 = (const float*)d_in[3];  const float* neb0 = (const float*)d_in[4];
    const float* new1 = (const float*)d_in[5];  const float* neb1 = (const float*)d_in[6];
    const float* eew0 = (const float*)d_in[7];  const float* eeb0 = (const float*)d_in[8];
    const float* eew1 = (const float*)d_in[9];  const float* eeb1 = (const float*)d_in[10];
    const float* mew0 = (const float*)d_in[11]; const float* meb0 = (const float*)d_in[12];
    const float* mew1 = (const float*)d_in[13]; const float* meb1 = (const float*)d_in[14];
    const float* mnw0 = (const float*)d_in[15]; const float* mnb0 = (const float*)d_in[16];
    const float* cw0  = (const float*)d_in[17]; const float* cb0  = (const float*)d_in[18];
    const float* cw1  = (const float*)d_in[19]; const float* cb1  = (const float*)d_in[20];
    const float* cw2  = (const float*)d_in[21]; const float* cb2  = (const float*)d_in[22];

    const int N = in_sizes[0] / NIN;   // 20000
    const int E = in_sizes[2] / 2;     // 100000
    const int* srcj = eidx;            // edge_index[0] = j (source)
    const int* tgti = eidx + E;        // edge_index[1] = i (target)

    float* ws  = (float*)d_ws;
    float* nf0 = ws;                                  // N*ND
    float* nfA = nf0 + (size_t)N * ND;                // N*ND
    float* nfB = nfA + (size_t)N * ND;                // N*ND
    float* ef0 = nfB + (size_t)N * ND;                // E*ED
    float* ef  = ef0 + (size_t)E * ED;                // E*ED

    const int eblocks = (E + TE - 1) / TE;

    node_embed_k<<<N, 128, 0, stream>>>(x, new0, neb0, new1, neb1, nf0, nfA);
    edge_embed_k<<<eblocks, 256, 0, stream>>>(ea, eew0, eeb0, eew1, eeb1, ef0, ef, E);

    const int nf_elems = N * ND;
    const int n4 = nf_elems / 4;
    const int zgrid = (n4 + 255) / 256;

    float* cur = nfA;
    float* nxt = nfB;
    for (int s = 0; s < 4; s++) {
        zero_k<<<zgrid, 256, 0, stream>>>(nxt, n4);
        edge_step_k<<<eblocks, 256, 0, stream>>>(srcj, tgti, nf0, cur, ef0, ef, nxt,
                                                 mew0, meb0, mew1, meb1, mnw0, mnb0, E);
        float* tmp = cur; cur = nxt; nxt = tmp;
    }

    classify_k<<<eblocks, 256, 0, stream>>>(ef, cw0, cb0, cw1, cb1, cw2, cb2,
                                            (float*)d_out, E);
}

// Round 5
// 1555.298 us; speedup vs baseline: 3.8469x; 1.8245x over previous
//
#include <hip/hip_runtime.h>
#include <hip/hip_bf16.h>

#define ND 128
#define ED 128
#define NIN 128
#define EIN 291
#define HH 64
#define TE 16    // edges per block in scalar tiled kernels
#define TM 32    // edges per block in MFMA edge_step

typedef __attribute__((ext_vector_type(8))) short short8;
typedef __attribute__((ext_vector_type(4))) float float4_;

__device__ __forceinline__ unsigned short f2bf(float f)
{
    union { float f; unsigned u; } v; v.f = f;
    unsigned u = v.u;
    unsigned r = (u + 0x7FFFu + ((u >> 16) & 1u)) >> 16;  // RNE
    return (unsigned short)r;
}

// Zero a float buffer.
__global__ __launch_bounds__(256) void zero_k(float* __restrict__ p, int n4)
{
    int idx = blockIdx.x * 256 + threadIdx.x;
    if (idx < n4) ((float4*)p)[idx] = make_float4(0.f, 0.f, 0.f, 0.f);
}

// One-time weight prep: transpose + fp32->bf16.
// w0T[64][768] <- mew0[768][64]; w1T[128][64] <- mew1[64][128]; wmT[128][384] <- mnw0[384][128]
__global__ __launch_bounds__(256) void wprep_k(
    const float* __restrict__ mew0, const float* __restrict__ mew1, const float* __restrict__ mnw0,
    unsigned short* __restrict__ w0T, unsigned short* __restrict__ w1T, unsigned short* __restrict__ wmT)
{
    int idx = blockIdx.x * 256 + threadIdx.x;
    if (idx < 49152) {                       // w0T
        int c = idx / 768, k = idx % 768;
        w0T[idx] = f2bf(mew0[k * 64 + c]);
    } else if (idx < 57344) {                // w1T
        int j = idx - 49152;
        int c = j / 64, k = j % 64;
        w1T[j] = f2bf(mew1[k * 128 + c]);
    } else if (idx < 106496) {               // wmT
        int j = idx - 57344;
        int c = j / 384, k = j % 384;
        wmT[j] = f2bf(mnw0[k * 128 + c]);
    }
}

// nf0/nf = MLP(x): NIN->128 (ReLU) ->ND. One block (128 thr) per node.
__global__ __launch_bounds__(128) void node_embed_k(
    const float* __restrict__ x, const float* __restrict__ w0, const float* __restrict__ b0,
    const float* __restrict__ w1, const float* __restrict__ b1,
    float* __restrict__ nf0, float* __restrict__ nf)
{
    int node = blockIdx.x;
    int t = threadIdx.x;
    __shared__ float xin[NIN];
    __shared__ float h[128];
    xin[t] = x[node * NIN + t];
    __syncthreads();
    float acc = b0[t];
#pragma unroll 8
    for (int k = 0; k < NIN; k++) acc += xin[k] * w0[k * 128 + t];
    h[t] = fmaxf(acc, 0.f);
    __syncthreads();
    float acc2 = b1[t];
#pragma unroll 8
    for (int k = 0; k < 128; k++) acc2 += h[k] * w1[k * ND + t];
    nf0[node * ND + t] = acc2;
    nf[node * ND + t] = acc2;
}

// ef0/ef = MLP(edge_attr): EIN->64 (ReLU) ->ED. TE edges per 256-thr block.
__global__ __launch_bounds__(256) void edge_embed_k(
    const float* __restrict__ ea, const float* __restrict__ w0, const float* __restrict__ b0,
    const float* __restrict__ w1, const float* __restrict__ b1,
    float* __restrict__ ef0, float* __restrict__ ef, int E)
{
    int t = threadIdx.x;
    int e0 = blockIdx.x * TE;
    __shared__ float in2[TE][EIN];
    __shared__ float h[TE][HH];
    for (int r = 0; r < TE; r++) {
        int e = e0 + r; if (e >= E) e = E - 1;
        for (int p = t; p < EIN; p += 256) in2[r][p] = ea[(size_t)e * EIN + p];
    }
    __syncthreads();
    {
        int c = t & 63, eg = t >> 6;
        float acc[4];
#pragma unroll
        for (int q = 0; q < 4; q++) acc[q] = b0[c];
#pragma unroll 8
        for (int k = 0; k < EIN; k++) {
            float w = w0[k * HH + c];
#pragma unroll
            for (int q = 0; q < 4; q++) acc[q] += in2[eg * 4 + q][k] * w;
        }
#pragma unroll
        for (int q = 0; q < 4; q++) h[eg * 4 + q][c] = fmaxf(acc[q], 0.f);
    }
    __syncthreads();
    {
        int c2 = t & 127, eh = t >> 7;
        float acc[8];
#pragma unroll
        for (int q = 0; q < 8; q++) acc[q] = b1[c2];
#pragma unroll 8
        for (int k = 0; k < HH; k++) {
            float w = w1[k * ED + c2];
#pragma unroll
            for (int q = 0; q < 8; q++) acc[q] += h[eh * 8 + q][k] * w;
        }
#pragma unroll
        for (int q = 0; q < 8; q++) {
            int e = e0 + eh * 8 + q;
            if (e < E) {
                ef0[(size_t)e * ED + c2] = acc[q];
                ef[(size_t)e * ED + c2] = acc[q];
            }
        }
    }
}

// MFMA MPN step: 32 edges/block, 256 thr (4 waves).
// L1: in[32][768] x w0T -> h[32][64] (ReLU)
// L2: h x w1T -> ef[32][128] (ReLU, in-place update + LDS copy)
// MSG: [in[:,0:256]|efn] x wmT -> msg[32][128] (ReLU) -> atomicAdd nfn[i]
__global__ __launch_bounds__(256) void edge_step_k(
    const int* __restrict__ srcj, const int* __restrict__ tgti,
    const float* __restrict__ nf0, const float* __restrict__ nfc,
    const float* __restrict__ ef0, float* __restrict__ ef,
    float* __restrict__ nfn,
    const unsigned short* __restrict__ w0T, const float* __restrict__ meb0,
    const unsigned short* __restrict__ w1T, const float* __restrict__ meb1,
    const unsigned short* __restrict__ wmT, const float* __restrict__ mnb0, int E)
{
    const int t = threadIdx.x;
    const int e0 = blockIdx.x * TM;
    __shared__ unsigned short in_bf[TM][776];   // 768 + 8 pad (16B-aligned rows)
    __shared__ unsigned short h_bf[TM][72];     // 64 + 8 pad
    __shared__ unsigned short efn_bf[TM][136];  // 128 + 8 pad
    __shared__ int sidx[2 * TM];                // [0..TM): i(target), [TM..): j(source)

    if (t < 2 * TM) {
        int r = t & (TM - 1);
        int e = e0 + r; if (e >= E) e = E - 1;
        sidx[t] = (t < TM) ? tgti[e] : srcj[e];
    }
    __syncthreads();

    // ---- stage 6 x 128-float segments per edge, fp32->bf16 ----
    {
        int lane32 = t & 31;
#pragma unroll
        for (int it = 0; it < 24; it++) {
            int rowseg = it * 8 + (t >> 5);     // 0..191
            int seg = rowseg >> 5;              // 0..5
            int r = rowseg & 31;
            const float* src;
            if (seg < 4) {
                int node = sidx[(seg >= 2 ? TM : 0) + r];
                const float* base = (seg & 1) ? nfc : nf0;
                src = base + (size_t)node * ND;
            } else {
                int e = e0 + r; if (e >= E) e = E - 1;
                src = ((seg == 4) ? ef0 : ef) + (size_t)e * ED;
            }
            float4 v = *(const float4*)(src + lane32 * 4);
            unsigned lo = (unsigned)f2bf(v.x) | ((unsigned)f2bf(v.y) << 16);
            unsigned hi = (unsigned)f2bf(v.z) | ((unsigned)f2bf(v.w) << 16);
            *(uint2*)&in_bf[r][seg * 128 + lane32 * 4] = make_uint2(lo, hi);
        }
    }
    __syncthreads();

    const int w = t >> 6, lane = t & 63, quad = lane >> 4, n16 = lane & 15;
    const int m = w & 1;          // M-tile (edges 16m..16m+15)

    // ---- layer 1: K=768, N=64. wave: M-tile m, N-tiles {(w>>1)*2, +1} ----
    {
        const int cb = (w >> 1) * 32;
        float4_ acc0 = {0.f, 0.f, 0.f, 0.f}, acc1 = acc0;
        const unsigned short* arow = &in_bf[m * 16 + n16][quad * 8];
        const unsigned short* b0p = w0T + (size_t)(cb + n16) * 768 + quad * 8;
        const unsigned short* b1p = w0T + (size_t)(cb + 16 + n16) * 768 + quad * 8;
#pragma unroll 4
        for (int kc = 0; kc < 24; kc++) {
            short8 a  = *(const short8*)(arow + kc * 32);
            short8 b0 = *(const short8*)(b0p + kc * 32);
            short8 b1 = *(const short8*)(b1p + kc * 32);
            acc0 = __builtin_amdgcn_mfma_f32_16x16x32_bf16(a, b0, acc0, 0, 0, 0);
            acc1 = __builtin_amdgcn_mfma_f32_16x16x32_bf16(a, b1, acc1, 0, 0, 0);
        }
#pragma unroll
        for (int t2 = 0; t2 < 2; t2++) {
            int c = cb + t2 * 16 + n16;
            float bias = meb0[c];
            float4_ ac = t2 ? acc1 : acc0;
#pragma unroll
            for (int r4 = 0; r4 < 4; r4++) {
                int row = m * 16 + quad * 4 + r4;
                h_bf[row][c] = f2bf(fmaxf(ac[r4] + bias, 0.f));
            }
        }
    }
    __syncthreads();

    // ---- layer 2: K=64, N=128. wave: M-tile m, N-tiles {(w>>1)*4 .. +3} ----
    {
        const int cb = (w >> 1) * 64;
        float4_ acc[4];
#pragma unroll
        for (int q = 0; q < 4; q++) acc[q] = (float4_){0.f, 0.f, 0.f, 0.f};
#pragma unroll
        for (int kc = 0; kc < 2; kc++) {
            short8 a = *(const short8*)&h_bf[m * 16 + n16][kc * 32 + quad * 8];
#pragma unroll
            for (int tt = 0; tt < 4; tt++) {
                short8 b = *(const short8*)(w1T + (size_t)(cb + tt * 16 + n16) * 64 + kc * 32 + quad * 8);
                acc[tt] = __builtin_amdgcn_mfma_f32_16x16x32_bf16(a, b, acc[tt], 0, 0, 0);
            }
        }
#pragma unroll
        for (int tt = 0; tt < 4; tt++) {
            int c = cb + tt * 16 + n16;
            float bias = meb1[c];
#pragma unroll
            for (int r4 = 0; r4 < 4; r4++) {
                int row = m * 16 + quad * 4 + r4;
                float v = fmaxf(acc[tt][r4] + bias, 0.f);
                efn_bf[row][c] = f2bf(v);
                int e = e0 + row;
                if (e < E) ef[(size_t)e * ED + c] = v;
            }
        }
    }
    __syncthreads();

    // ---- message: K=384 (in cols 0..255 then efn), N=128; scatter-add ----
    {
        const int cb = (w >> 1) * 64;
        float4_ acc[4];
#pragma unroll
        for (int q = 0; q < 4; q++) acc[q] = (float4_){0.f, 0.f, 0.f, 0.f};
#pragma unroll 4
        for (int kc = 0; kc < 12; kc++) {
            const unsigned short* ap = (kc < 8)
                ? &in_bf[m * 16 + n16][kc * 32 + quad * 8]
                : &efn_bf[m * 16 + n16][(kc - 8) * 32 + quad * 8];
            short8 a = *(const short8*)ap;
#pragma unroll
            for (int tt = 0; tt < 4; tt++) {
                short8 b = *(const short8*)(wmT + (size_t)(cb + tt * 16 + n16) * 384 + kc * 32 + quad * 8);
                acc[tt] = __builtin_amdgcn_mfma_f32_16x16x32_bf16(a, b, acc[tt], 0, 0, 0);
            }
        }
#pragma unroll
        for (int tt = 0; tt < 4; tt++) {
            int c = cb + tt * 16 + n16;
            float bias = mnb0[c];
#pragma unroll
            for (int r4 = 0; r4 < 4; r4++) {
                int row = m * 16 + quad * 4 + r4;
                int e = e0 + row;
                if (e < E) {
                    float v = fmaxf(acc[tt][r4] + bias, 0.f);
                    atomicAdd(&nfn[(size_t)sidx[row] * ND + c], v);
                }
            }
        }
    }
}

// out = MLP(ef): ED->64 (ReLU) ->32 (ReLU) ->1. TE edges per 256-thr block.
__global__ __launch_bounds__(256) void classify_k(
    const float* __restrict__ ef,
    const float* __restrict__ cw0, const float* __restrict__ cb0,
    const float* __restrict__ cw1, const float* __restrict__ cb1,
    const float* __restrict__ cw2, const float* __restrict__ cb2,
    float* __restrict__ out, int E)
{
    int t = threadIdx.x;
    int e0 = blockIdx.x * TE;
    __shared__ float efs[TE][ED];
    __shared__ float h0[TE][64];
    __shared__ float h1[TE][32];
    for (int r = 0; r < TE; r += 2) {
        int rr = r + (t >> 7);
        int e = e0 + rr; if (e >= E) e = E - 1;
        efs[rr][t & 127] = ef[(size_t)e * ED + (t & 127)];
    }
    __syncthreads();
    {
        int c = t & 63, eg = t >> 6;
        float acc[4];
#pragma unroll
        for (int q = 0; q < 4; q++) acc[q] = cb0[c];
#pragma unroll 8
        for (int k = 0; k < ED; k++) {
            float w = cw0[k * 64 + c];
#pragma unroll
            for (int q = 0; q < 4; q++) acc[q] += efs[eg * 4 + q][k] * w;
        }
#pragma unroll
        for (int q = 0; q < 4; q++) h0[eg * 4 + q][c] = fmaxf(acc[q], 0.f);
    }
    __syncthreads();
    {
        int c = t & 31, eg = t >> 5;
        float acc[2];
#pragma unroll
        for (int q = 0; q < 2; q++) acc[q] = cb1[c];
#pragma unroll 8
        for (int k = 0; k < 64; k++) {
            float w = cw1[k * 32 + c];
#pragma unroll
            for (int q = 0; q < 2; q++) acc[q] += h0[eg * 2 + q][k] * w;
        }
#pragma unroll
        for (int q = 0; q < 2; q++) h1[eg * 2 + q][c] = fmaxf(acc[q], 0.f);
    }
    __syncthreads();
    if (t < TE) {
        int e = e0 + t;
        if (e < E) {
            float a = cb2[0];
#pragma unroll
            for (int k = 0; k < 32; k++) a += h1[t][k] * cw2[k];
            out[e] = a;
        }
    }
}

extern "C" void kernel_launch(void* const* d_in, const int* in_sizes, int n_in,
                              void* d_out, int out_size, void* d_ws, size_t ws_size,
                              hipStream_t stream)
{
    const float* x    = (const float*)d_in[0];
    const float* ea   = (const float*)d_in[1];
    const int*   eidx = (const int*)d_in[2];
    const float* new0 = (const float*)d_in[3];  const float* neb0 = (const float*)d_in[4];
    const float* new1 = (const float*)d_in[5];  const float* neb1 = (const float*)d_in[6];
    const float* eew0 = (const float*)d_in[7];  const float* eeb0 = (const float*)d_in[8];
    const float* eew1 = (const float*)d_in[9];  const float* eeb1 = (const float*)d_in[10];
    const float* mew0 = (const float*)d_in[11]; const float* meb0 = (const float*)d_in[12];
    const float* mew1 = (const float*)d_in[13]; const float* meb1 = (const float*)d_in[14];
    const float* mnw0 = (const float*)d_in[15]; const float* mnb0 = (const float*)d_in[16];
    const float* cw0  = (const float*)d_in[17]; const float* cb0  = (const float*)d_in[18];
    const float* cw1  = (const float*)d_in[19]; const float* cb1  = (const float*)d_in[20];
    const float* cw2  = (const float*)d_in[21]; const float* cb2  = (const float*)d_in[22];

    const int N = in_sizes[0] / NIN;   // 20000
    const int E = in_sizes[2] / 2;     // 100000
    const int* srcj = eidx;            // edge_index[0] = j (source)
    const int* tgti = eidx + E;        // edge_index[1] = i (target)

    float* ws  = (float*)d_ws;
    float* nf0 = ws;
    float* nfA = nf0 + (size_t)N * ND;
    float* nfB = nfA + (size_t)N * ND;
    float* ef0 = nfB + (size_t)N * ND;
    float* ef  = ef0 + (size_t)E * ED;
    unsigned short* w0T = (unsigned short*)(ef + (size_t)E * ED);  // [64][768]
    unsigned short* w1T = w0T + 49152;                             // [128][64]
    unsigned short* wmT = w1T + 8192;                              // [128][384]

    const int eblocks16 = (E + TE - 1) / TE;
    const int eblocks32 = (E + TM - 1) / TM;

    wprep_k<<<(106496 + 255) / 256, 256, 0, stream>>>(mew0, mew1, mnw0, w0T, w1T, wmT);
    node_embed_k<<<N, 128, 0, stream>>>(x, new0, neb0, new1, neb1, nf0, nfA);
    edge_embed_k<<<eblocks16, 256, 0, stream>>>(ea, eew0, eeb0, eew1, eeb1, ef0, ef, E);

    const int n4 = (N * ND) / 4;
    const int zgrid = (n4 + 255) / 256;

    float* cur = nfA;
    float* nxt = nfB;
    for (int s = 0; s < 4; s++) {
        zero_k<<<zgrid, 256, 0, stream>>>(nxt, n4);
        edge_step_k<<<eblocks32, 256, 0, stream>>>(srcj, tgti, nf0, cur, ef0, ef, nxt,
                                                   w0T, meb0, w1T, meb1, wmT, mnb0, E);
        float* tmp = cur; cur = nxt; nxt = tmp;
    }

    classify_k<<<eblocks16, 256, 0, stream>>>(ef, cw0, cb0, cw1, cb1, cw2, cb2,
                                              (float*)d_out, E);
}

// Round 6
// 1356.754 us; speedup vs baseline: 4.4099x; 1.1463x over previous
//
#include <hip/hip_runtime.h>
#include <hip/hip_bf16.h>

#define ND 128
#define ED 128
#define NIN 128
#define EIN 291
#define KPAD 320   // EIN padded to multiple of 32
#define HH 64
#define TE 16      // edges per block in scalar tiled kernels
#define TM 32      // edges per block in MFMA kernels

typedef __attribute__((ext_vector_type(8))) short short8;
typedef __attribute__((ext_vector_type(4))) float float4_;

__device__ __forceinline__ unsigned short f2bf(float f)
{
    union { float f; unsigned u; } v; v.f = f;
    unsigned u = v.u;
    unsigned r = (u + 0x7FFFu + ((u >> 16) & 1u)) >> 16;  // RNE
    return (unsigned short)r;
}
__device__ __forceinline__ float bf2f(unsigned short s)
{
    union { unsigned u; float f; } v; v.u = ((unsigned)s) << 16;
    return v.f;
}

// Zero a float buffer.
__global__ __launch_bounds__(256) void zero_k(float* __restrict__ p, int n4)
{
    int idx = blockIdx.x * 256 + threadIdx.x;
    if (idx < n4) ((float4*)p)[idx] = make_float4(0.f, 0.f, 0.f, 0.f);
}

// Convert fp32 accumulator -> bf16 activation buffer. n4 = elems/4.
__global__ __launch_bounds__(256) void f2bf_k(const float* __restrict__ src,
                                              unsigned short* __restrict__ dst, int n4)
{
    int idx = blockIdx.x * 256 + threadIdx.x;
    if (idx < n4) {
        float4 v = ((const float4*)src)[idx];
        unsigned lo = (unsigned)f2bf(v.x) | ((unsigned)f2bf(v.y) << 16);
        unsigned hi = (unsigned)f2bf(v.z) | ((unsigned)f2bf(v.w) << 16);
        ((uint2*)dst)[idx] = make_uint2(lo, hi);
    }
}

// One-time weight prep: transpose + fp32->bf16 (+ zero-pad K for edge-embed L1).
// w0T[64][768]<-mew0 ; w1T[128][64]<-mew1 ; wmT[128][384]<-mnw0 ;
// w0eT[64][KPAD]<-eew0 (k>=291 zero) ; w1eT[128][64]<-eew1
__global__ __launch_bounds__(256) void wprep_k(
    const float* __restrict__ mew0, const float* __restrict__ mew1, const float* __restrict__ mnw0,
    const float* __restrict__ eew0, const float* __restrict__ eew1,
    unsigned short* __restrict__ w0T, unsigned short* __restrict__ w1T,
    unsigned short* __restrict__ wmT, unsigned short* __restrict__ w0eT,
    unsigned short* __restrict__ w1eT)
{
    int idx = blockIdx.x * 256 + threadIdx.x;
    if (idx < 49152) {
        int c = idx / 768, k = idx % 768;
        w0T[idx] = f2bf(mew0[k * 64 + c]);
    } else if (idx < 57344) {
        int j = idx - 49152; int c = j / 64, k = j % 64;
        w1T[j] = f2bf(mew1[k * 128 + c]);
    } else if (idx < 106496) {
        int j = idx - 57344; int c = j / 384, k = j % 384;
        wmT[j] = f2bf(mnw0[k * 128 + c]);
    } else if (idx < 126976) {
        int j = idx - 106496; int c = j / KPAD, k = j % KPAD;
        w0eT[j] = (k < EIN) ? f2bf(eew0[k * 64 + c]) : (unsigned short)0;
    } else if (idx < 135168) {
        int j = idx - 126976; int c = j / 64, k = j % 64;
        w1eT[j] = f2bf(eew1[k * 128 + c]);
    }
}

// nf0/nf = MLP(x): NIN->128 (ReLU) ->ND. One block (128 thr) per node. bf16 out.
__global__ __launch_bounds__(128) void node_embed_k(
    const float* __restrict__ x, const float* __restrict__ w0, const float* __restrict__ b0,
    const float* __restrict__ w1, const float* __restrict__ b1,
    unsigned short* __restrict__ nf0_bf, unsigned short* __restrict__ nf_bf)
{
    int node = blockIdx.x;
    int t = threadIdx.x;
    __shared__ float xin[NIN];
    __shared__ float h[128];
    xin[t] = x[node * NIN + t];
    __syncthreads();
    float acc = b0[t];
#pragma unroll 8
    for (int k = 0; k < NIN; k++) acc += xin[k] * w0[k * 128 + t];
    h[t] = fmaxf(acc, 0.f);
    __syncthreads();
    float acc2 = b1[t];
#pragma unroll 8
    for (int k = 0; k < 128; k++) acc2 += h[k] * w1[k * ND + t];
    unsigned short v = f2bf(acc2);
    nf0_bf[(size_t)node * ND + t] = v;
    nf_bf[(size_t)node * ND + t] = v;
}

// MFMA edge embed: 32 edges/block. L1 K=KPAD(320) N=64 (ReLU), L2 K=64 N=128 (no ReLU).
__global__ __launch_bounds__(256) void edge_embed_k(
    const float* __restrict__ ea,
    const unsigned short* __restrict__ w0eT, const float* __restrict__ b0,
    const unsigned short* __restrict__ w1eT, const float* __restrict__ b1,
    unsigned short* __restrict__ ef0_bf, unsigned short* __restrict__ ef_bf, int E)
{
    const int t = threadIdx.x;
    const int e0 = blockIdx.x * TM;
    __shared__ unsigned short ea_bf[TM][KPAD + 8];  // 328 shorts/row
    __shared__ unsigned short h_bf[TM][72];

    // stage + convert + zero-pad
    for (int r = 0; r < TM; r++) {
        int e = e0 + r; if (e >= E) e = E - 1;
        const float* src = ea + (size_t)e * EIN;
        for (int p = t; p < KPAD; p += 256)
            ea_bf[r][p] = (p < EIN) ? f2bf(src[p]) : (unsigned short)0;
    }
    __syncthreads();

    const int w = t >> 6, lane = t & 63, quad = lane >> 4, n16 = lane & 15;
    const int m = w & 1;

    // L1: wave -> M-tile m, N-tiles {(w>>1)*2, +1}
    {
        const int cb = (w >> 1) * 32;
        float4_ acc0 = {0.f, 0.f, 0.f, 0.f}, acc1 = acc0;
        const unsigned short* arow = &ea_bf[m * 16 + n16][quad * 8];
        const unsigned short* b0p = w0eT + (size_t)(cb + n16) * KPAD + quad * 8;
        const unsigned short* b1p = w0eT + (size_t)(cb + 16 + n16) * KPAD + quad * 8;
#pragma unroll 5
        for (int kc = 0; kc < 10; kc++) {
            short8 a  = *(const short8*)(arow + kc * 32);
            short8 bb0 = *(const short8*)(b0p + kc * 32);
            short8 bb1 = *(const short8*)(b1p + kc * 32);
            acc0 = __builtin_amdgcn_mfma_f32_16x16x32_bf16(a, bb0, acc0, 0, 0, 0);
            acc1 = __builtin_amdgcn_mfma_f32_16x16x32_bf16(a, bb1, acc1, 0, 0, 0);
        }
#pragma unroll
        for (int t2 = 0; t2 < 2; t2++) {
            int c = cb + t2 * 16 + n16;
            float bias = b0[c];
            float4_ ac = t2 ? acc1 : acc0;
#pragma unroll
            for (int r4 = 0; r4 < 4; r4++)
                h_bf[m * 16 + quad * 4 + r4][c] = f2bf(fmaxf(ac[r4] + bias, 0.f));
        }
    }
    __syncthreads();

    // L2: K=64, N=128; no ReLU. bf16 stores to ef0/ef.
    {
        const int cb = (w >> 1) * 64;
        float4_ acc[4];
#pragma unroll
        for (int q = 0; q < 4; q++) acc[q] = (float4_){0.f, 0.f, 0.f, 0.f};
#pragma unroll
        for (int kc = 0; kc < 2; kc++) {
            short8 a = *(const short8*)&h_bf[m * 16 + n16][kc * 32 + quad * 8];
#pragma unroll
            for (int tt = 0; tt < 4; tt++) {
                short8 b = *(const short8*)(w1eT + (size_t)(cb + tt * 16 + n16) * 64 + kc * 32 + quad * 8);
                acc[tt] = __builtin_amdgcn_mfma_f32_16x16x32_bf16(a, b, acc[tt], 0, 0, 0);
            }
        }
#pragma unroll
        for (int tt = 0; tt < 4; tt++) {
            int c = cb + tt * 16 + n16;
            float bias = b1[c];
#pragma unroll
            for (int r4 = 0; r4 < 4; r4++) {
                int row = m * 16 + quad * 4 + r4;
                int e = e0 + row;
                if (e < E) {
                    unsigned short v = f2bf(acc[tt][r4] + bias);
                    ef0_bf[(size_t)e * ED + c] = v;
                    ef_bf[(size_t)e * ED + c] = v;
                }
            }
        }
    }
}

// MFMA MPN step: 32 edges/block. All activations bf16; staging is pure copies.
__global__ __launch_bounds__(256) void edge_step_k(
    const int* __restrict__ srcj, const int* __restrict__ tgti,
    const unsigned short* __restrict__ nf0_bf, const unsigned short* __restrict__ nf_bf,
    const unsigned short* __restrict__ ef0_bf, unsigned short* __restrict__ ef_bf,
    float* __restrict__ nfn,
    const unsigned short* __restrict__ w0T, const float* __restrict__ meb0,
    const unsigned short* __restrict__ w1T, const float* __restrict__ meb1,
    const unsigned short* __restrict__ wmT, const float* __restrict__ mnb0, int E)
{
    const int t = threadIdx.x;
    const int e0 = blockIdx.x * TM;
    __shared__ unsigned short in_bf[TM][776];   // 768 + 8 pad
    __shared__ unsigned short h_bf[TM][72];
    __shared__ unsigned short efn_bf[TM][136];
    __shared__ int sidx[2 * TM];

    if (t < 2 * TM) {
        int r = t & (TM - 1);
        int e = e0 + r; if (e >= E) e = E - 1;
        sidx[t] = (t < TM) ? tgti[e] : srcj[e];
    }
    __syncthreads();

    // stage 6 segs x 32 rows x 128 bf16 (short8 copies, no conversion)
    {
        int lane16 = t & 15;
        int rs0 = t >> 4;
#pragma unroll
        for (int it = 0; it < 12; it++) {
            int rowseg = it * 16 + rs0;     // 0..191
            int seg = rowseg >> 5, r = rowseg & 31;
            const unsigned short* src;
            if (seg < 4) {
                int node = sidx[(seg >= 2 ? TM : 0) + r];
                const unsigned short* base = (seg & 1) ? nf_bf : nf0_bf;
                src = base + (size_t)node * ND;
            } else {
                int e = e0 + r; if (e >= E) e = E - 1;
                src = ((seg == 4) ? ef0_bf : ef_bf) + (size_t)e * ED;
            }
            *(short8*)&in_bf[r][seg * 128 + lane16 * 8] = *(const short8*)(src + lane16 * 8);
        }
    }
    __syncthreads();

    const int w = t >> 6, lane = t & 63, quad = lane >> 4, n16 = lane & 15;
    const int m = w & 1;

    // L1: K=768, N=64
    {
        const int cb = (w >> 1) * 32;
        float4_ acc0 = {0.f, 0.f, 0.f, 0.f}, acc1 = acc0;
        const unsigned short* arow = &in_bf[m * 16 + n16][quad * 8];
        const unsigned short* b0p = w0T + (size_t)(cb + n16) * 768 + quad * 8;
        const unsigned short* b1p = w0T + (size_t)(cb + 16 + n16) * 768 + quad * 8;
#pragma unroll 4
        for (int kc = 0; kc < 24; kc++) {
            short8 a  = *(const short8*)(arow + kc * 32);
            short8 bb0 = *(const short8*)(b0p + kc * 32);
            short8 bb1 = *(const short8*)(b1p + kc * 32);
            acc0 = __builtin_amdgcn_mfma_f32_16x16x32_bf16(a, bb0, acc0, 0, 0, 0);
            acc1 = __builtin_amdgcn_mfma_f32_16x16x32_bf16(a, bb1, acc1, 0, 0, 0);
        }
#pragma unroll
        for (int t2 = 0; t2 < 2; t2++) {
            int c = cb + t2 * 16 + n16;
            float bias = meb0[c];
            float4_ ac = t2 ? acc1 : acc0;
#pragma unroll
            for (int r4 = 0; r4 < 4; r4++)
                h_bf[m * 16 + quad * 4 + r4][c] = f2bf(fmaxf(ac[r4] + bias, 0.f));
        }
    }
    __syncthreads();

    // L2: K=64, N=128 (ReLU), ef_bf in-place + LDS copy
    {
        const int cb = (w >> 1) * 64;
        float4_ acc[4];
#pragma unroll
        for (int q = 0; q < 4; q++) acc[q] = (float4_){0.f, 0.f, 0.f, 0.f};
#pragma unroll
        for (int kc = 0; kc < 2; kc++) {
            short8 a = *(const short8*)&h_bf[m * 16 + n16][kc * 32 + quad * 8];
#pragma unroll
            for (int tt = 0; tt < 4; tt++) {
                short8 b = *(const short8*)(w1T + (size_t)(cb + tt * 16 + n16) * 64 + kc * 32 + quad * 8);
                acc[tt] = __builtin_amdgcn_mfma_f32_16x16x32_bf16(a, b, acc[tt], 0, 0, 0);
            }
        }
#pragma unroll
        for (int tt = 0; tt < 4; tt++) {
            int c = cb + tt * 16 + n16;
            float bias = meb1[c];
#pragma unroll
            for (int r4 = 0; r4 < 4; r4++) {
                int row = m * 16 + quad * 4 + r4;
                unsigned short v = f2bf(fmaxf(acc[tt][r4] + bias, 0.f));
                efn_bf[row][c] = v;
                int e = e0 + row;
                if (e < E) ef_bf[(size_t)e * ED + c] = v;
            }
        }
    }
    __syncthreads();

    // MSG: K=384, N=128; fp32 atomic scatter-add at target i
    {
        const int cb = (w >> 1) * 64;
        float4_ acc[4];
#pragma unroll
        for (int q = 0; q < 4; q++) acc[q] = (float4_){0.f, 0.f, 0.f, 0.f};
#pragma unroll 4
        for (int kc = 0; kc < 12; kc++) {
            const unsigned short* ap = (kc < 8)
                ? &in_bf[m * 16 + n16][kc * 32 + quad * 8]
                : &efn_bf[m * 16 + n16][(kc - 8) * 32 + quad * 8];
            short8 a = *(const short8*)ap;
#pragma unroll
            for (int tt = 0; tt < 4; tt++) {
                short8 b = *(const short8*)(wmT + (size_t)(cb + tt * 16 + n16) * 384 + kc * 32 + quad * 8);
                acc[tt] = __builtin_amdgcn_mfma_f32_16x16x32_bf16(a, b, acc[tt], 0, 0, 0);
            }
        }
#pragma unroll
        for (int tt = 0; tt < 4; tt++) {
            int c = cb + tt * 16 + n16;
            float bias = mnb0[c];
#pragma unroll
            for (int r4 = 0; r4 < 4; r4++) {
                int row = m * 16 + quad * 4 + r4;
                int e = e0 + row;
                if (e < E)
                    atomicAdd(&nfn[(size_t)sidx[row] * ND + c],
                              fmaxf(acc[tt][r4] + bias, 0.f));
            }
        }
    }
}

// out = MLP(ef): ED->64 (ReLU) ->32 (ReLU) ->1. TE edges per 256-thr block. bf16 in.
__global__ __launch_bounds__(256) void classify_k(
    const unsigned short* __restrict__ ef_bf,
    const float* __restrict__ cw0, const float* __restrict__ cb0,
    const float* __restrict__ cw1, const float* __restrict__ cb1,
    const float* __restrict__ cw2, const float* __restrict__ cb2,
    float* __restrict__ out, int E)
{
    int t = threadIdx.x;
    int e0 = blockIdx.x * TE;
    __shared__ float efs[TE][ED];
    __shared__ float h0[TE][64];
    __shared__ float h1[TE][32];
    for (int r = 0; r < TE; r += 2) {
        int rr = r + (t >> 7);
        int e = e0 + rr; if (e >= E) e = E - 1;
        efs[rr][t & 127] = bf2f(ef_bf[(size_t)e * ED + (t & 127)]);
    }
    __syncthreads();
    {
        int c = t & 63, eg = t >> 6;
        float acc[4];
#pragma unroll
        for (int q = 0; q < 4; q++) acc[q] = cb0[c];
#pragma unroll 8
        for (int k = 0; k < ED; k++) {
            float w = cw0[k * 64 + c];
#pragma unroll
            for (int q = 0; q < 4; q++) acc[q] += efs[eg * 4 + q][k] * w;
        }
#pragma unroll
        for (int q = 0; q < 4; q++) h0[eg * 4 + q][c] = fmaxf(acc[q], 0.f);
    }
    __syncthreads();
    {
        int c = t & 31, eg = t >> 5;
        float acc[2];
#pragma unroll
        for (int q = 0; q < 2; q++) acc[q] = cb1[c];
#pragma unroll 8
        for (int k = 0; k < 64; k++) {
            float w = cw1[k * 32 + c];
#pragma unroll
            for (int q = 0; q < 2; q++) acc[q] += h0[eg * 2 + q][k] * w;
        }
#pragma unroll
        for (int q = 0; q < 2; q++) h1[eg * 2 + q][c] = fmaxf(acc[q], 0.f);
    }
    __syncthreads();
    if (t < TE) {
        int e = e0 + t;
        if (e < E) {
            float a = cb2[0];
#pragma unroll
            for (int k = 0; k < 32; k++) a += h1[t][k] * cw2[k];
            out[e] = a;
        }
    }
}

extern "C" void kernel_launch(void* const* d_in, const int* in_sizes, int n_in,
                              void* d_out, int out_size, void* d_ws, size_t ws_size,
                              hipStream_t stream)
{
    const float* x    = (const float*)d_in[0];
    const float* ea   = (const float*)d_in[1];
    const int*   eidx = (const int*)d_in[2];
    const float* new0 = (const float*)d_in[3];  const float* neb0 = (const float*)d_in[4];
    const float* new1 = (const float*)d_in[5];  const float* neb1 = (const float*)d_in[6];
    const float* eew0 = (const float*)d_in[7];  const float* eeb0 = (const float*)d_in[8];
    const float* eew1 = (const float*)d_in[9];  const float* eeb1 = (const float*)d_in[10];
    const float* mew0 = (const float*)d_in[11]; const float* meb0 = (const float*)d_in[12];
    const float* mew1 = (const float*)d_in[13]; const float* meb1 = (const float*)d_in[14];
    const float* mnw0 = (const float*)d_in[15]; const float* mnb0 = (const float*)d_in[16];
    const float* cw0  = (const float*)d_in[17]; const float* cb0  = (const float*)d_in[18];
    const float* cw1  = (const float*)d_in[19]; const float* cb1  = (const float*)d_in[20];
    const float* cw2  = (const float*)d_in[21]; const float* cb2  = (const float*)d_in[22];

    const int N = in_sizes[0] / NIN;   // 20000
    const int E = in_sizes[2] / 2;     // 100000
    const int* srcj = eidx;            // edge_index[0] = j (source)
    const int* tgti = eidx + E;        // edge_index[1] = i (target)

    char* wsb = (char*)d_ws;
    float* nfn = (float*)wsb;                               // N*ND fp32 accum
    unsigned short* nf0_bf = (unsigned short*)(nfn + (size_t)N * ND);
    unsigned short* nf_bf  = nf0_bf + (size_t)N * ND;
    unsigned short* ef0_bf = nf_bf + (size_t)N * ND;
    unsigned short* ef_bf  = ef0_bf + (size_t)E * ED;
    unsigned short* w0T  = ef_bf + (size_t)E * ED;          // [64][768]
    unsigned short* w1T  = w0T + 49152;                     // [128][64]
    unsigned short* wmT  = w1T + 8192;                      // [128][384]
    unsigned short* w0eT = wmT + 49152;                     // [64][KPAD]
    unsigned short* w1eT = w0eT + 64 * KPAD;                // [128][64]

    const int eblocks16 = (E + TE - 1) / TE;
    const int eblocks32 = (E + TM - 1) / TM;

    wprep_k<<<(135168 + 255) / 256, 256, 0, stream>>>(mew0, mew1, mnw0, eew0, eew1,
                                                      w0T, w1T, wmT, w0eT, w1eT);
    node_embed_k<<<N, 128, 0, stream>>>(x, new0, neb0, new1, neb1, nf0_bf, nf_bf);
    edge_embed_k<<<eblocks32, 256, 0, stream>>>(ea, w0eT, eeb0, w1eT, eeb1,
                                                ef0_bf, ef_bf, E);

    const int n4 = (N * ND) / 4;
    const int zgrid = (n4 + 255) / 256;

    for (int s = 0; s < 4; s++) {
        zero_k<<<zgrid, 256, 0, stream>>>(nfn, n4);
        edge_step_k<<<eblocks32, 256, 0, stream>>>(srcj, tgti, nf0_bf, nf_bf,
                                                   ef0_bf, ef_bf, nfn,
                                                   w0T, meb0, w1T, meb1, wmT, mnb0, E);
        f2bf_k<<<zgrid, 256, 0, stream>>>(nfn, nf_bf, n4);
    }

    classify_k<<<eblocks16, 256, 0, stream>>>(ef_bf, cw0, cb0, cw1, cb1, cw2, cb2,
                                              (float*)d_out, E);
}

// Round 7
// 1319.145 us; speedup vs baseline: 4.5356x; 1.0285x over previous
//
#include <hip/hip_runtime.h>
#include <hip/hip_bf16.h>

#define ND 128
#define ED 128
#define NIN 128
#define EIN 291
#define KPAD 320   // EIN padded to multiple of 32
#define HH 64
#define TM 32      // edges per block in MFMA kernels

typedef __attribute__((ext_vector_type(8))) short short8;
typedef __attribute__((ext_vector_type(4))) float float4_;

__device__ __forceinline__ unsigned short f2bf(float f)
{
    union { float f; unsigned u; } v; v.f = f;
    unsigned u = v.u;
    unsigned r = (u + 0x7FFFu + ((u >> 16) & 1u)) >> 16;  // RNE
    return (unsigned short)r;
}
__device__ __forceinline__ float bf2f(unsigned short s)
{
    union { unsigned u; float f; } v; v.u = ((unsigned)s) << 16;
    return v.f;
}

// Zero a float buffer.
__global__ __launch_bounds__(256) void zero_k(float* __restrict__ p, int n4)
{
    int idx = blockIdx.x * 256 + threadIdx.x;
    if (idx < n4) ((float4*)p)[idx] = make_float4(0.f, 0.f, 0.f, 0.f);
}

// Fused: convert fp32 accumulator -> bf16 activations, then zero the accumulator.
__global__ __launch_bounds__(256) void f2bfz_k(float* __restrict__ src,
                                               unsigned short* __restrict__ dst, int n4)
{
    int idx = blockIdx.x * 256 + threadIdx.x;
    if (idx < n4) {
        float4 v = ((const float4*)src)[idx];
        unsigned lo = (unsigned)f2bf(v.x) | ((unsigned)f2bf(v.y) << 16);
        unsigned hi = (unsigned)f2bf(v.z) | ((unsigned)f2bf(v.w) << 16);
        ((uint2*)dst)[idx] = make_uint2(lo, hi);
        ((float4*)src)[idx] = make_float4(0.f, 0.f, 0.f, 0.f);
    }
}

// One-time weight prep: transpose + fp32->bf16 (+ zero-pad K for edge-embed L1).
__global__ __launch_bounds__(256) void wprep_k(
    const float* __restrict__ mew0, const float* __restrict__ mew1, const float* __restrict__ mnw0,
    const float* __restrict__ eew0, const float* __restrict__ eew1, const float* __restrict__ cw0,
    unsigned short* __restrict__ w0T, unsigned short* __restrict__ w1T,
    unsigned short* __restrict__ wmT, unsigned short* __restrict__ w0eT,
    unsigned short* __restrict__ w1eT, unsigned short* __restrict__ cw0T)
{
    int idx = blockIdx.x * 256 + threadIdx.x;
    if (idx < 49152) {
        int c = idx / 768, k = idx % 768;
        w0T[idx] = f2bf(mew0[k * 64 + c]);
    } else if (idx < 57344) {
        int j = idx - 49152; int c = j / 64, k = j % 64;
        w1T[j] = f2bf(mew1[k * 128 + c]);
    } else if (idx < 106496) {
        int j = idx - 57344; int c = j / 384, k = j % 384;
        wmT[j] = f2bf(mnw0[k * 128 + c]);
    } else if (idx < 126976) {
        int j = idx - 106496; int c = j / KPAD, k = j % KPAD;
        w0eT[j] = (k < EIN) ? f2bf(eew0[k * 64 + c]) : (unsigned short)0;
    } else if (idx < 135168) {
        int j = idx - 126976; int c = j / 64, k = j % 64;
        w1eT[j] = f2bf(eew1[k * 128 + c]);
    } else if (idx < 143360) {
        int j = idx - 135168; int c = j / 128, k = j % 128;
        cw0T[j] = f2bf(cw0[k * 64 + c]);
    }
}

// nf0/nf = MLP(x): NIN->128 (ReLU) ->ND. One block (128 thr) per node. bf16 out.
__global__ __launch_bounds__(128) void node_embed_k(
    const float* __restrict__ x, const float* __restrict__ w0, const float* __restrict__ b0,
    const float* __restrict__ w1, const float* __restrict__ b1,
    unsigned short* __restrict__ nf0_bf, unsigned short* __restrict__ nf_bf)
{
    int node = blockIdx.x;
    int t = threadIdx.x;
    __shared__ float xin[NIN];
    __shared__ float h[128];
    xin[t] = x[node * NIN + t];
    __syncthreads();
    float acc = b0[t];
#pragma unroll 8
    for (int k = 0; k < NIN; k++) acc += xin[k] * w0[k * 128 + t];
    h[t] = fmaxf(acc, 0.f);
    __syncthreads();
    float acc2 = b1[t];
#pragma unroll 8
    for (int k = 0; k < 128; k++) acc2 += h[k] * w1[k * ND + t];
    unsigned short v = f2bf(acc2);
    nf0_bf[(size_t)node * ND + t] = v;
    nf_bf[(size_t)node * ND + t] = v;
}

// MFMA edge embed: 32 edges/block. L1 K=KPAD(320) N=64 (ReLU), L2 K=64 N=128 (no ReLU).
__global__ __launch_bounds__(256) void edge_embed_k(
    const float* __restrict__ ea,
    const unsigned short* __restrict__ w0eT, const float* __restrict__ b0,
    const unsigned short* __restrict__ w1eT, const float* __restrict__ b1,
    unsigned short* __restrict__ ef0_bf, unsigned short* __restrict__ ef_bf, int E)
{
    const int t = threadIdx.x;
    const int e0 = blockIdx.x * TM;
    __shared__ unsigned short ea_bf[TM][KPAD + 8];
    __shared__ unsigned short h_bf[TM][72];

    for (int r = 0; r < TM; r++) {
        int e = e0 + r; if (e >= E) e = E - 1;
        const float* src = ea + (size_t)e * EIN;
        for (int p = t; p < KPAD; p += 256)
            ea_bf[r][p] = (p < EIN) ? f2bf(src[p]) : (unsigned short)0;
    }
    __syncthreads();

    const int w = t >> 6, lane = t & 63, quad = lane >> 4, n16 = lane & 15;
    const int m = w & 1;

    {
        const int cb = (w >> 1) * 32;
        float4_ acc0 = {0.f, 0.f, 0.f, 0.f}, acc1 = acc0;
        const unsigned short* arow = &ea_bf[m * 16 + n16][quad * 8];
        const unsigned short* b0p = w0eT + (size_t)(cb + n16) * KPAD + quad * 8;
        const unsigned short* b1p = w0eT + (size_t)(cb + 16 + n16) * KPAD + quad * 8;
#pragma unroll 5
        for (int kc = 0; kc < 10; kc++) {
            short8 a  = *(const short8*)(arow + kc * 32);
            short8 bb0 = *(const short8*)(b0p + kc * 32);
            short8 bb1 = *(const short8*)(b1p + kc * 32);
            acc0 = __builtin_amdgcn_mfma_f32_16x16x32_bf16(a, bb0, acc0, 0, 0, 0);
            acc1 = __builtin_amdgcn_mfma_f32_16x16x32_bf16(a, bb1, acc1, 0, 0, 0);
        }
#pragma unroll
        for (int t2 = 0; t2 < 2; t2++) {
            int c = cb + t2 * 16 + n16;
            float bias = b0[c];
            float4_ ac = t2 ? acc1 : acc0;
#pragma unroll
            for (int r4 = 0; r4 < 4; r4++)
                h_bf[m * 16 + quad * 4 + r4][c] = f2bf(fmaxf(ac[r4] + bias, 0.f));
        }
    }
    __syncthreads();

    {
        const int cb = (w >> 1) * 64;
        float4_ acc[4];
#pragma unroll
        for (int q = 0; q < 4; q++) acc[q] = (float4_){0.f, 0.f, 0.f, 0.f};
#pragma unroll
        for (int kc = 0; kc < 2; kc++) {
            short8 a = *(const short8*)&h_bf[m * 16 + n16][kc * 32 + quad * 8];
#pragma unroll
            for (int tt = 0; tt < 4; tt++) {
                short8 b = *(const short8*)(w1eT + (size_t)(cb + tt * 16 + n16) * 64 + kc * 32 + quad * 8);
                acc[tt] = __builtin_amdgcn_mfma_f32_16x16x32_bf16(a, b, acc[tt], 0, 0, 0);
            }
        }
#pragma unroll
        for (int tt = 0; tt < 4; tt++) {
            int c = cb + tt * 16 + n16;
            float bias = b1[c];
#pragma unroll
            for (int r4 = 0; r4 < 4; r4++) {
                int row = m * 16 + quad * 4 + r4;
                int e = e0 + row;
                if (e < E) {
                    unsigned short v = f2bf(acc[tt][r4] + bias);
                    ef0_bf[(size_t)e * ED + c] = v;
                    ef_bf[(size_t)e * ED + c] = v;
                }
            }
        }
    }
}

// MFMA MPN step: 32 edges/block; A-fragments loaded DIRECTLY from global
// (no LDS staging — MFMA A layout A[m=lane&15][k=quad*8+j] means each lane
// reads 16B contiguous from its own edge's feature row).
__global__ __launch_bounds__(256) void edge_step_k(
    const int* __restrict__ srcj, const int* __restrict__ tgti,
    const unsigned short* __restrict__ nf0_bf, const unsigned short* __restrict__ nf_bf,
    const unsigned short* __restrict__ ef0_bf, unsigned short* __restrict__ ef_bf,
    float* __restrict__ nfn,
    const unsigned short* __restrict__ w0T, const float* __restrict__ meb0,
    const unsigned short* __restrict__ w1T, const float* __restrict__ meb1,
    const unsigned short* __restrict__ wmT, const float* __restrict__ mnb0, int E)
{
    const int t = threadIdx.x;
    const int e0 = blockIdx.x * TM;
    __shared__ unsigned short h_bf[TM][72];
    __shared__ unsigned short efn_bf[TM][136];
    __shared__ int sidx[TM];

    if (t < TM) {
        int e = e0 + t; if (e >= E) e = E - 1;
        sidx[t] = tgti[e];
    }

    const int w = t >> 6, lane = t & 63, quad = lane >> 4, n16 = lane & 15;
    const int m = w & 1;
    const int erow = m * 16 + n16;
    int ec = e0 + erow; if (ec >= E) ec = E - 1;
    const int ti = tgti[ec], sj = srcj[ec];
    const unsigned short* pA0 = nf0_bf + (size_t)ti * ND + quad * 8;
    const unsigned short* pA1 = nf_bf  + (size_t)ti * ND + quad * 8;
    const unsigned short* pA2 = nf0_bf + (size_t)sj * ND + quad * 8;
    const unsigned short* pA3 = nf_bf  + (size_t)sj * ND + quad * 8;
    const unsigned short* pA4 = ef0_bf + (size_t)ec * ED + quad * 8;
    const unsigned short* pA5 = ef_bf  + (size_t)ec * ED + quad * 8;

    // ---- L1: K=768, N=64 ----
    {
        const int cb = (w >> 1) * 32;
        float4_ acc0 = {0.f, 0.f, 0.f, 0.f}, acc1 = acc0;
        const unsigned short* b0p = w0T + (size_t)(cb + n16) * 768 + quad * 8;
        const unsigned short* b1p = b0p + (size_t)16 * 768;
        const unsigned short* pAs[6] = {pA0, pA1, pA2, pA3, pA4, pA5};
#pragma unroll
        for (int kc = 0; kc < 24; kc++) {
            short8 a  = *(const short8*)(pAs[kc >> 2] + (kc & 3) * 32);
            short8 bb0 = *(const short8*)(b0p + kc * 32);
            short8 bb1 = *(const short8*)(b1p + kc * 32);
            acc0 = __builtin_amdgcn_mfma_f32_16x16x32_bf16(a, bb0, acc0, 0, 0, 0);
            acc1 = __builtin_amdgcn_mfma_f32_16x16x32_bf16(a, bb1, acc1, 0, 0, 0);
        }
#pragma unroll
        for (int t2 = 0; t2 < 2; t2++) {
            int c = cb + t2 * 16 + n16;
            float bias = meb0[c];
            float4_ ac = t2 ? acc1 : acc0;
#pragma unroll
            for (int r4 = 0; r4 < 4; r4++)
                h_bf[m * 16 + quad * 4 + r4][c] = f2bf(fmaxf(ac[r4] + bias, 0.f));
        }
    }
    __syncthreads();

    // ---- L2: K=64, N=128 (ReLU), ef_bf in-place + LDS copy ----
    {
        const int cb = (w >> 1) * 64;
        float4_ acc[4];
#pragma unroll
        for (int q = 0; q < 4; q++) acc[q] = (float4_){0.f, 0.f, 0.f, 0.f};
#pragma unroll
        for (int kc = 0; kc < 2; kc++) {
            short8 a = *(const short8*)&h_bf[m * 16 + n16][kc * 32 + quad * 8];
#pragma unroll
            for (int tt = 0; tt < 4; tt++) {
                short8 b = *(const short8*)(w1T + (size_t)(cb + tt * 16 + n16) * 64 + kc * 32 + quad * 8);
                acc[tt] = __builtin_amdgcn_mfma_f32_16x16x32_bf16(a, b, acc[tt], 0, 0, 0);
            }
        }
#pragma unroll
        for (int tt = 0; tt < 4; tt++) {
            int c = cb + tt * 16 + n16;
            float bias = meb1[c];
#pragma unroll
            for (int r4 = 0; r4 < 4; r4++) {
                int row = m * 16 + quad * 4 + r4;
                unsigned short v = f2bf(fmaxf(acc[tt][r4] + bias, 0.f));
                efn_bf[row][c] = v;
                int e = e0 + row;
                if (e < E) ef_bf[(size_t)e * ED + c] = v;
            }
        }
    }
    __syncthreads();

    // ---- MSG: K=384 (nf0_i|nf_i from global, efn from LDS), N=128 ----
    {
        const int cb = (w >> 1) * 64;
        float4_ acc[4];
#pragma unroll
        for (int q = 0; q < 4; q++) acc[q] = (float4_){0.f, 0.f, 0.f, 0.f};
        const unsigned short* pAs2[2] = {pA0, pA1};
#pragma unroll
        for (int kc = 0; kc < 12; kc++) {
            short8 a;
            if (kc < 8) a = *(const short8*)(pAs2[kc >> 2] + (kc & 3) * 32);
            else        a = *(const short8*)&efn_bf[erow][(kc - 8) * 32 + quad * 8];
#pragma unroll
            for (int tt = 0; tt < 4; tt++) {
                short8 b = *(const short8*)(wmT + (size_t)(cb + tt * 16 + n16) * 384 + kc * 32 + quad * 8);
                acc[tt] = __builtin_amdgcn_mfma_f32_16x16x32_bf16(a, b, acc[tt], 0, 0, 0);
            }
        }
#pragma unroll
        for (int tt = 0; tt < 4; tt++) {
            int c = cb + tt * 16 + n16;
            float bias = mnb0[c];
#pragma unroll
            for (int r4 = 0; r4 < 4; r4++) {
                int row = m * 16 + quad * 4 + r4;
                int e = e0 + row;
                if (e < E)
                    atomicAdd(&nfn[(size_t)sidx[row] * ND + c],
                              fmaxf(acc[tt][r4] + bias, 0.f));
            }
        }
    }
}

// classify: L1 (128->64, ReLU) via MFMA with direct-global A; L2/L3 scalar fp32.
__global__ __launch_bounds__(256) void classify_k(
    const unsigned short* __restrict__ ef_bf,
    const unsigned short* __restrict__ cw0T, const float* __restrict__ cb0,
    const float* __restrict__ cw1, const float* __restrict__ cb1,
    const float* __restrict__ cw2, const float* __restrict__ cb2,
    float* __restrict__ out, int E)
{
    const int t = threadIdx.x;
    const int e0 = blockIdx.x * TM;
    __shared__ unsigned short h0_bf[TM][72];
    __shared__ float h1[TM][33];

    const int w = t >> 6, lane = t & 63, quad = lane >> 4, n16 = lane & 15;
    const int m = w & 1;
    const int erow = m * 16 + n16;
    int ec = e0 + erow; if (ec >= E) ec = E - 1;
    const unsigned short* pa = ef_bf + (size_t)ec * ED + quad * 8;

    {
        const int cb = (w >> 1) * 32;
        float4_ acc0 = {0.f, 0.f, 0.f, 0.f}, acc1 = acc0;
        const unsigned short* b0p = cw0T + (size_t)(cb + n16) * 128 + quad * 8;
        const unsigned short* b1p = b0p + (size_t)16 * 128;
#pragma unroll
        for (int kc = 0; kc < 4; kc++) {
            short8 a  = *(const short8*)(pa + kc * 32);
            short8 bb0 = *(const short8*)(b0p + kc * 32);
            short8 bb1 = *(const short8*)(b1p + kc * 32);
            acc0 = __builtin_amdgcn_mfma_f32_16x16x32_bf16(a, bb0, acc0, 0, 0, 0);
            acc1 = __builtin_amdgcn_mfma_f32_16x16x32_bf16(a, bb1, acc1, 0, 0, 0);
        }
#pragma unroll
        for (int t2 = 0; t2 < 2; t2++) {
            int c = cb + t2 * 16 + n16;
            float bias = cb0[c];
            float4_ ac = t2 ? acc1 : acc0;
#pragma unroll
            for (int r4 = 0; r4 < 4; r4++)
                h0_bf[m * 16 + quad * 4 + r4][c] = f2bf(fmaxf(ac[r4] + bias, 0.f));
        }
    }
    __syncthreads();

    // L2 scalar: 32 edges x 32 cols, fp32 weights.
    {
        int c = t & 31;
        int rbase = (t >> 5) * 4;
#pragma unroll
        for (int q = 0; q < 4; q++) {
            int r = rbase + q;
            float acc = cb1[c];
#pragma unroll 8
            for (int k = 0; k < 64; k++) acc += bf2f(h0_bf[r][k]) * cw1[k * 32 + c];
            h1[r][c] = fmaxf(acc, 0.f);
        }
    }
    __syncthreads();

    if (t < TM) {
        int e = e0 + t;
        if (e < E) {
            float a = cb2[0];
#pragma unroll
            for (int k = 0; k < 32; k++) a += h1[t][k] * cw2[k];
            out[e] = a;
        }
    }
}

extern "C" void kernel_launch(void* const* d_in, const int* in_sizes, int n_in,
                              void* d_out, int out_size, void* d_ws, size_t ws_size,
                              hipStream_t stream)
{
    const float* x    = (const float*)d_in[0];
    const float* ea   = (const float*)d_in[1];
    const int*   eidx = (const int*)d_in[2];
    const float* new0 = (const float*)d_in[3];  const float* neb0 = (const float*)d_in[4];
    const float* new1 = (const float*)d_in[5];  const float* neb1 = (const float*)d_in[6];
    const float* eew0 = (const float*)d_in[7];  const float* eeb0 = (const float*)d_in[8];
    const float* eew1 = (const float*)d_in[9];  const float* eeb1 = (const float*)d_in[10];
    const float* mew0 = (const float*)d_in[11]; const float* meb0 = (const float*)d_in[12];
    const float* mew1 = (const float*)d_in[13]; const float* meb1 = (const float*)d_in[14];
    const float* mnw0 = (const float*)d_in[15]; const float* mnb0 = (const float*)d_in[16];
    const float* cw0  = (const float*)d_in[17]; const float* cb0  = (const float*)d_in[18];
    const float* cw1  = (const float*)d_in[19]; const float* cb1  = (const float*)d_in[20];
    const float* cw2  = (const float*)d_in[21]; const float* cb2  = (const float*)d_in[22];

    const int N = in_sizes[0] / NIN;   // 20000
    const int E = in_sizes[2] / 2;     // 100000
    const int* srcj = eidx;            // edge_index[0] = j (source)
    const int* tgti = eidx + E;        // edge_index[1] = i (target)

    char* wsb = (char*)d_ws;
    float* nfn = (float*)wsb;                               // N*ND fp32 accum
    unsigned short* nf0_bf = (unsigned short*)(nfn + (size_t)N * ND);
    unsigned short* nf_bf  = nf0_bf + (size_t)N * ND;
    unsigned short* ef0_bf = nf_bf + (size_t)N * ND;
    unsigned short* ef_bf  = ef0_bf + (size_t)E * ED;
    unsigned short* w0T  = ef_bf + (size_t)E * ED;          // [64][768]
    unsigned short* w1T  = w0T + 49152;                     // [128][64]
    unsigned short* wmT  = w1T + 8192;                      // [128][384]
    unsigned short* w0eT = wmT + 49152;                     // [64][KPAD]
    unsigned short* w1eT = w0eT + 64 * KPAD;                // [128][64]
    unsigned short* cw0T = w1eT + 8192;                     // [64][128]

    const int eblocks32 = (E + TM - 1) / TM;

    wprep_k<<<(143360 + 255) / 256, 256, 0, stream>>>(mew0, mew1, mnw0, eew0, eew1, cw0,
                                                      w0T, w1T, wmT, w0eT, w1eT, cw0T);
    node_embed_k<<<N, 128, 0, stream>>>(x, new0, neb0, new1, neb1, nf0_bf, nf_bf);
    edge_embed_k<<<eblocks32, 256, 0, stream>>>(ea, w0eT, eeb0, w1eT, eeb1,
                                                ef0_bf, ef_bf, E);

    const int n4 = (N * ND) / 4;
    const int zgrid = (n4 + 255) / 256;
    zero_k<<<zgrid, 256, 0, stream>>>(nfn, n4);

    for (int s = 0; s < 4; s++) {
        edge_step_k<<<eblocks32, 256, 0, stream>>>(srcj, tgti, nf0_bf, nf_bf,
                                                   ef0_bf, ef_bf, nfn,
                                                   w0T, meb0, w1T, meb1, wmT, mnb0, E);
        f2bfz_k<<<zgrid, 256, 0, stream>>>(nfn, nf_bf, n4);
    }

    classify_k<<<eblocks32, 256, 0, stream>>>(ef_bf, cw0T, cb0, cw1, cb1, cw2, cb2,
                                              (float*)d_out, E);
}